// Round 1
// baseline (496.625 us; speedup 1.0000x reference)
//
#include <hip/hip_runtime.h>

// GPT2 self-attention fused pipeline for MI355X (gfx950).
// B=2, L=2048, E=1024, H=16, HD=64.
// d_out = [out (B*L*E f32)] ++ [attn (B*H*L*L f32)]

#define B_ 2
#define L_ 2048
#define E_ 1024
#define H_ 16
#define HD_ 64

typedef __attribute__((ext_vector_type(8))) __bf16 bf16x8;
typedef __attribute__((ext_vector_type(4))) __bf16 bf16x4;
typedef __attribute__((ext_vector_type(4))) float f32x4;

typedef __attribute__((address_space(1))) const void gvoid_t;
typedef __attribute__((address_space(3))) void lvoid_t;

__device__ __forceinline__ void g2l16(const void* g, void* l) {
  // async global->LDS, 16B per lane; LDS dest = wave-uniform base + lane*16
  __builtin_amdgcn_global_load_lds((gvoid_t*)g, (lvoid_t*)l, 16, 0, 0);
}

__device__ __forceinline__ f32x4 mfma16(bf16x8 a, bf16x8 b, f32x4 c) {
  return __builtin_amdgcn_mfma_f32_16x16x32_bf16(a, b, c, 0, 0, 0);
}

// ---------------------------------------------------------------- converts
__global__ __launch_bounds__(256) void f32_to_bf16_vec(
    const float* __restrict__ in, __bf16* __restrict__ out, int n) {
  int i = (blockIdx.x * blockDim.x + threadIdx.x) * 4;
  if (i >= n) return;
  float4 v = *(const float4*)(in + i);
  bf16x4 o = {(__bf16)v.x, (__bf16)v.y, (__bf16)v.z, (__bf16)v.w};
  *(bf16x4*)(out + i) = o;
}

// out[c][r] = (bf16) in[r][c]   (in: [R][C] f32 row-major)
__global__ __launch_bounds__(256) void transpose_to_bf16(
    const float* __restrict__ in, __bf16* __restrict__ out, int R, int C) {
  __shared__ __bf16 tile[32][33];
  int c0 = blockIdx.x * 32, r0 = blockIdx.y * 32;
  int tx = threadIdx.x, ty = threadIdx.y;
  for (int i = ty; i < 32; i += 8)
    tile[i][tx] = (__bf16)in[(size_t)(r0 + i) * C + c0 + tx];
  __syncthreads();
  for (int i = ty; i < 32; i += 8)
    out[(size_t)(c0 + i) * R + r0 + tx] = tile[tx][i];
}

// ---------------------------------------------------------------- GEMM
// C[M][N] = A[M][K] @ Bt[N][K]^T  (+bias[n]).  bf16 inputs, fp32 accum.
// mode 0: QKV epilogue scatter -> Qb/Kb [bh][L][64] bf16, Vt [bh][64][L] bf16
// mode 1: outF[m][n] = acc + bias  (f32)
__global__ __launch_bounds__(256) void gemm_bf16_k(
    const __bf16* __restrict__ A, const __bf16* __restrict__ Bt,
    const float* __restrict__ bias, int M, int N, int K, int mode,
    float* __restrict__ outF, __bf16* __restrict__ Qb,
    __bf16* __restrict__ Kb, __bf16* __restrict__ Vt) {
  const f32x4 fz = {0.f, 0.f, 0.f, 0.f};
  int n0 = blockIdx.x * 128, m0 = blockIdx.y * 128;
  int w = threadIdx.x >> 6, l = threadIdx.x & 63;
  int wr = w >> 1, wc = w & 1, lr = l & 15, lg = l >> 4;
  __shared__ __bf16 Al[128 * 64];  // [128 rows][64 k] linear, 128B rows
  __shared__ __bf16 Bl[128 * 64];
  f32x4 acc[4][4];
#pragma unroll
  for (int i = 0; i < 4; ++i)
#pragma unroll
    for (int j = 0; j < 4; ++j) acc[i][j] = fz;

  for (int k0 = 0; k0 < K; k0 += 64) {
    __syncthreads();  // previous-iter readers done before overwrite
#pragma unroll
    for (int i = 0; i < 4; ++i) {
      int base = (w * 4 + i) * 1024;  // byte offset, wave-uniform
      int boff = base + l * 16;
      int row = boff >> 7, ch = (boff >> 4) & 7;
      g2l16(A + (size_t)(m0 + row) * K + k0 + ch * 8, (char*)Al + base);
      g2l16(Bt + (size_t)(n0 + row) * K + k0 + ch * 8, (char*)Bl + base);
    }
    __syncthreads();  // drains vmcnt -> LDS valid
    bf16x8 af[2][4], bfr[2][4];
#pragma unroll
    for (int ks = 0; ks < 2; ++ks)
#pragma unroll
      for (int f = 0; f < 4; ++f) {
        af[ks][f]  = *(const bf16x8*)&Al[(wr * 64 + f * 16 + lr) * 64 + ks * 32 + lg * 8];
        bfr[ks][f] = *(const bf16x8*)&Bl[(wc * 64 + f * 16 + lr) * 64 + ks * 32 + lg * 8];
      }
#pragma unroll
    for (int ks = 0; ks < 2; ++ks)
#pragma unroll
      for (int mf = 0; mf < 4; ++mf)
#pragma unroll
        for (int nf = 0; nf < 4; ++nf)
          acc[mf][nf] = mfma16(af[ks][mf], bfr[ks][nf], acc[mf][nf]);
  }

#pragma unroll
  for (int mf = 0; mf < 4; ++mf)
#pragma unroll
    for (int nf = 0; nf < 4; ++nf) {
      int ncol = n0 + wc * 64 + nf * 16 + lr;
      float bv = bias[ncol];
#pragma unroll
      for (int jj = 0; jj < 4; ++jj) {
        int mr = m0 + wr * 64 + mf * 16 + lg * 4 + jj;  // D: row=(lane>>4)*4+reg
        float v = acc[mf][nf][jj] + bv;
        if (mode == 1) {
          outF[(size_t)mr * N + ncol] = v;
        } else {
          int bb = mr >> 11, lp = mr & 2047;   // batch, position
          int reg = ncol >> 10, nn = ncol & 1023;
          int hh = nn >> 6, dd = nn & 63;
          size_t bh = (size_t)bb * H_ + hh;
          __bf16 bv16 = (__bf16)v;  // reference rounds q/k to bf16; v bf16 ok
          if (reg == 0)      Qb[(bh * L_ + lp) * HD_ + dd] = bv16;
          else if (reg == 1) Kb[(bh * L_ + lp) * HD_ + dd] = bv16;
          else               Vt[(bh * HD_ + dd) * L_ + lp] = bv16;
        }
      }
    }
}

// ---------------------------------------------------------------- attention
// 1 WG = (b, h, 64-row q-tile). 4 waves x 16 q-rows. Chunks of 64 keys.
// Two-pass exact softmax; attn rows written fp32; PV via bf16 MFMA.
__global__ __launch_bounds__(256) void attn_fused(
    const __bf16* __restrict__ Qb, const __bf16* __restrict__ Kb,
    const __bf16* __restrict__ Vt, const float* __restrict__ amask,
    float* __restrict__ attn_out, __bf16* __restrict__ merged) {
  const f32x4 fz = {0.f, 0.f, 0.f, 0.f};
  int id = blockIdx.x;
  int qt = id & 31, h = (id >> 5) & 15, b = id >> 9;
  int bh = b * H_ + h;
  int w = threadIdx.x >> 6, l = threadIdx.x & 63;
  int lr = l & 15, lg = l >> 4;
  const __bf16* Qh = Qb + (size_t)bh * L_ * HD_;
  const __bf16* Kh = Kb + (size_t)bh * L_ * HD_;
  const __bf16* Vh = Vt + (size_t)bh * HD_ * L_;
  float* attn = attn_out + (size_t)bh * L_ * L_;
  const float* mb = amask + (size_t)b * L_;
  int q0 = qt * 64 + w * 16;

  __shared__ __bf16 Pl[4][16 * 72];  // per-wave P tile, padded stride 72

  bf16x8 qf0 = *(const bf16x8*)&Qh[(size_t)(q0 + lr) * HD_ + lg * 8];
  bf16x8 qf1 = *(const bf16x8*)&Qh[(size_t)(q0 + lr) * HD_ + 32 + lg * 8];

  float m_run[4], l_run[4];
#pragma unroll
  for (int jj = 0; jj < 4; ++jj) { m_run[jj] = -3.0e38f; l_run[jj] = 0.f; }

  int ncc = qt + 1;  // causal: only chunks 0..qt have any unmasked cols

  auto computeS = [&](int c, float sf[4][4]) {
#pragma unroll
    for (int cf = 0; cf < 4; ++cf) {
      const __bf16* kb = &Kh[(size_t)(c * 64 + cf * 16 + lr) * HD_];
      bf16x8 k0 = *(const bf16x8*)&kb[lg * 8];
      bf16x8 k1 = *(const bf16x8*)&kb[32 + lg * 8];
      f32x4 acc = fz;
      acc = mfma16(qf0, k0, acc);
      acc = mfma16(qf1, k1, acc);
      int col = c * 64 + cf * 16 + lr;
      float mk = mb[col];
#pragma unroll
      for (int jj = 0; jj < 4; ++jj) {
        int row = q0 + lg * 4 + jj;
        // replicate ref numerics: bf16(acc) then /8 (exact), mask=-9984(bf16
        // of -10000), then +attn_mask in fp32.
        float s = (float)(__bf16)acc[jj] * 0.125f;
        if (col > row) s = -9984.0f;
        sf[cf][jj] = s + mk;
      }
    }
  };

  // ---- pass 1: row max + sumexp (online)
  for (int c = 0; c < ncc; ++c) {
    float sf[4][4];
    computeS(c, sf);
#pragma unroll
    for (int jj = 0; jj < 4; ++jj) {
      float mx = fmaxf(fmaxf(sf[0][jj], sf[1][jj]), fmaxf(sf[2][jj], sf[3][jj]));
#pragma unroll
      for (int t = 1; t < 16; t <<= 1) mx = fmaxf(mx, __shfl_xor(mx, t, 64));
      float mn = fmaxf(m_run[jj], mx);
      float se = __expf(sf[0][jj] - mn) + __expf(sf[1][jj] - mn) +
                 __expf(sf[2][jj] - mn) + __expf(sf[3][jj] - mn);
#pragma unroll
      for (int t = 1; t < 16; t <<= 1) se += __shfl_xor(se, t, 64);
      l_run[jj] = l_run[jj] * __expf(m_run[jj] - mn) + se;
      m_run[jj] = mn;
    }
  }

  float inv_l[4];
#pragma unroll
  for (int jj = 0; jj < 4; ++jj) inv_l[jj] = 1.0f / l_run[jj];

  f32x4 o[4] = {fz, fz, fz, fz};

  // ---- pass 2: recompute scores (deterministic), write attn, PV
  for (int c = 0; c < ncc; ++c) {
    float sf[4][4];
    computeS(c, sf);
#pragma unroll
    for (int cf = 0; cf < 4; ++cf) {
      int col = c * 64 + cf * 16 + lr;
#pragma unroll
      for (int jj = 0; jj < 4; ++jj) {
        int row = q0 + lg * 4 + jj;
        float p = __expf(sf[cf][jj] - m_run[jj]) * inv_l[jj];
        attn[(size_t)row * L_ + col] = p;  // masked cols give exactly 0
        Pl[w][(lg * 4 + jj) * 72 + cf * 16 + lr] = (__bf16)p;
      }
    }
    bf16x8 pf0 = *(const bf16x8*)&Pl[w][lr * 72 + lg * 8];
    bf16x8 pf1 = *(const bf16x8*)&Pl[w][lr * 72 + 32 + lg * 8];
#pragma unroll
    for (int dt = 0; dt < 4; ++dt) {
      const __bf16* vb = &Vh[(size_t)(dt * 16 + lr) * L_ + c * 64];
      bf16x8 v0 = *(const bf16x8*)&vb[lg * 8];
      bf16x8 v1 = *(const bf16x8*)&vb[32 + lg * 8];
      o[dt] = mfma16(pf0, v0, o[dt]);
      o[dt] = mfma16(pf1, v1, o[dt]);
    }
  }

  // merged head outputs [B*L][E] bf16 (input of out-proj GEMM)
#pragma unroll
  for (int dt = 0; dt < 4; ++dt)
#pragma unroll
    for (int jj = 0; jj < 4; ++jj) {
      int row = q0 + lg * 4 + jj;
      merged[((size_t)b * L_ + row) * E_ + h * HD_ + dt * 16 + lr] =
          (__bf16)o[dt][jj];
    }

  // zero-fill fully-masked chunks (exp(-9984-m)==0 exactly in ref)
  for (int c = ncc; c < 32; ++c) {
#pragma unroll
    for (int jj = 0; jj < 4; ++jj) {
      int row = q0 + lg * 4 + jj;
      *(f32x4*)&attn[(size_t)row * L_ + c * 64 + lr * 4] = fz;
    }
  }
}

// ---------------------------------------------------------------- launch
extern "C" void kernel_launch(void* const* d_in, const int* in_sizes, int n_in,
                              void* d_out, int out_size, void* d_ws,
                              size_t ws_size, hipStream_t stream) {
  const float* x     = (const float*)d_in[0];
  const float* amask = (const float*)d_in[1];
  const float* W_in  = (const float*)d_in[2];
  const float* b_in  = (const float*)d_in[3];
  const float* W_out = (const float*)d_in[4];
  const float* b_out = (const float*)d_in[5];

  float* out  = (float*)d_out;
  float* attn = out + (size_t)B_ * L_ * E_;

  // workspace layout (needs ~48 MB)
  char* ws = (char*)d_ws;
  __bf16* xb     = (__bf16*)(ws + 0);
  __bf16* WtIn   = (__bf16*)(ws + 8388608);
  __bf16* WtOut  = (__bf16*)(ws + 14680064);
  __bf16* Qb     = (__bf16*)(ws + 16777216);
  __bf16* Kb     = (__bf16*)(ws + 25165824);
  __bf16* Vt     = (__bf16*)(ws + 33554432);
  __bf16* merged = (__bf16*)(ws + 41943040);

  int nx = B_ * L_ * E_;  // 4,194,304
  f32_to_bf16_vec<<<nx / (256 * 4), 256, 0, stream>>>(x, xb, nx);
  transpose_to_bf16<<<dim3(3 * E_ / 32, E_ / 32), dim3(32, 8), 0, stream>>>(
      W_in, WtIn, E_, 3 * E_);
  transpose_to_bf16<<<dim3(E_ / 32, E_ / 32), dim3(32, 8), 0, stream>>>(
      W_out, WtOut, E_, E_);

  // qkv = xb @ W_in + b_in, scattered to per-head Q/K (bf16) and V^T (bf16)
  gemm_bf16_k<<<dim3(3 * E_ / 128, B_ * L_ / 128), 256, 0, stream>>>(
      xb, WtIn, b_in, B_ * L_, 3 * E_, E_, 0, nullptr, Qb, Kb, Vt);

  attn_fused<<<B_ * H_ * (L_ / 64), 256, 0, stream>>>(Qb, Kb, Vt, amask, attn,
                                                      merged);

  // out = merged @ W_out + b_out
  gemm_bf16_k<<<dim3(E_ / 128, B_ * L_ / 128), 256, 0, stream>>>(
      merged, WtOut, b_out, B_ * L_, E_, E_, 1, out, nullptr, nullptr,
      nullptr);
}

// Round 2
// 495.287 us; speedup vs baseline: 1.0027x; 1.0027x over previous
//
#include <hip/hip_runtime.h>

// GPT2 self-attention fused pipeline for MI355X (gfx950).
// B=2, L=2048, E=1024, H=16, HD=64.
// d_out = [out (B*L*E f32)] ++ [attn (B*H*L*L f32)]

#define B_ 2
#define L_ 2048
#define E_ 1024
#define H_ 16
#define HD_ 64

typedef __attribute__((ext_vector_type(8))) __bf16 bf16x8;
typedef __attribute__((ext_vector_type(4))) __bf16 bf16x4;
typedef __attribute__((ext_vector_type(4))) float f32x4;

typedef __attribute__((address_space(1))) const void gvoid_t;
typedef __attribute__((address_space(3))) void lvoid_t;

__device__ __forceinline__ void g2l16(const void* g, void* l) {
  __builtin_amdgcn_global_load_lds((gvoid_t*)g, (lvoid_t*)l, 16, 0, 0);
}

__device__ __forceinline__ f32x4 mfma16(bf16x8 a, bf16x8 b, f32x4 c) {
  return __builtin_amdgcn_mfma_f32_16x16x32_bf16(a, b, c, 0, 0, 0);
}

// ---------------------------------------------------------------- converts
__global__ __launch_bounds__(256) void f32_to_bf16_vec(
    const float* __restrict__ in, __bf16* __restrict__ out, int n) {
  int i = (blockIdx.x * blockDim.x + threadIdx.x) * 4;
  if (i >= n) return;
  float4 v = *(const float4*)(in + i);
  bf16x4 o = {(__bf16)v.x, (__bf16)v.y, (__bf16)v.z, (__bf16)v.w};
  *(bf16x4*)(out + i) = o;
}

// out[c][r] = (bf16) in[r][c]   (in: [R][C] f32 row-major)
__global__ __launch_bounds__(256) void transpose_to_bf16(
    const float* __restrict__ in, __bf16* __restrict__ out, int R, int C) {
  __shared__ __bf16 tile[32][33];
  int c0 = blockIdx.x * 32, r0 = blockIdx.y * 32;
  int tx = threadIdx.x, ty = threadIdx.y;
  for (int i = ty; i < 32; i += 8)
    tile[i][tx] = (__bf16)in[(size_t)(r0 + i) * C + c0 + tx];
  __syncthreads();
  for (int i = ty; i < 32; i += 8)
    out[(size_t)(c0 + i) * R + r0 + tx] = tile[tx][i];
}

// ---------------------------------------------------------------- GEMM
// C[M][N] = A[M][K] @ Bt[N][K]^T  (+bias[n]).  bf16 inputs, fp32 accum.
// mode 0: QKV epilogue scatter -> Qb/Kb [bh][L][64] bf16, Vt [bh][64][L] bf16
// mode 1: outF[m][n] = acc + bias  (f32)
__global__ __launch_bounds__(256) void gemm_bf16_k(
    const __bf16* __restrict__ A, const __bf16* __restrict__ Bt,
    const float* __restrict__ bias, int M, int N, int K, int mode,
    float* __restrict__ outF, __bf16* __restrict__ Qb,
    __bf16* __restrict__ Kb, __bf16* __restrict__ Vt) {
  const f32x4 fz = {0.f, 0.f, 0.f, 0.f};
  int n0 = blockIdx.x * 128, m0 = blockIdx.y * 128;
  int w = threadIdx.x >> 6, l = threadIdx.x & 63;
  int wr = w >> 1, wc = w & 1, lr = l & 15, lg = l >> 4;
  __shared__ __bf16 Al[128 * 64];
  __shared__ __bf16 Bl[128 * 64];
  f32x4 acc[4][4];
#pragma unroll
  for (int i = 0; i < 4; ++i)
#pragma unroll
    for (int j = 0; j < 4; ++j) acc[i][j] = fz;

  for (int k0 = 0; k0 < K; k0 += 64) {
    __syncthreads();
#pragma unroll
    for (int i = 0; i < 4; ++i) {
      int base = (w * 4 + i) * 1024;
      int boff = base + l * 16;
      int row = boff >> 7, ch = (boff >> 4) & 7;
      g2l16(A + (size_t)(m0 + row) * K + k0 + ch * 8, (char*)Al + base);
      g2l16(Bt + (size_t)(n0 + row) * K + k0 + ch * 8, (char*)Bl + base);
    }
    __syncthreads();
    bf16x8 af[2][4], bfr[2][4];
#pragma unroll
    for (int ks = 0; ks < 2; ++ks)
#pragma unroll
      for (int f = 0; f < 4; ++f) {
        af[ks][f]  = *(const bf16x8*)&Al[(wr * 64 + f * 16 + lr) * 64 + ks * 32 + lg * 8];
        bfr[ks][f] = *(const bf16x8*)&Bl[(wc * 64 + f * 16 + lr) * 64 + ks * 32 + lg * 8];
      }
#pragma unroll
    for (int ks = 0; ks < 2; ++ks)
#pragma unroll
      for (int mf = 0; mf < 4; ++mf)
#pragma unroll
        for (int nf = 0; nf < 4; ++nf)
          acc[mf][nf] = mfma16(af[ks][mf], bfr[ks][nf], acc[mf][nf]);
  }

#pragma unroll
  for (int mf = 0; mf < 4; ++mf)
#pragma unroll
    for (int nf = 0; nf < 4; ++nf) {
      int ncol = n0 + wc * 64 + nf * 16 + lr;
      float bv = bias[ncol];
#pragma unroll
      for (int jj = 0; jj < 4; ++jj) {
        int mr = m0 + wr * 64 + mf * 16 + lg * 4 + jj;
        float v = acc[mf][nf][jj] + bv;
        if (mode == 1) {
          outF[(size_t)mr * N + ncol] = v;
        } else {
          int bb = mr >> 11, lp = mr & 2047;
          int reg = ncol >> 10, nn = ncol & 1023;
          int hh = nn >> 6, dd = nn & 63;
          size_t bh = (size_t)bb * H_ + hh;
          __bf16 bv16 = (__bf16)v;
          if (reg == 0)      Qb[(bh * L_ + lp) * HD_ + dd] = bv16;
          else if (reg == 1) Kb[(bh * L_ + lp) * HD_ + dd] = bv16;
          else               Vt[(bh * HD_ + dd) * L_ + lp] = bv16;
        }
      }
    }
}

// ---------------------------------------------------------------- flash pass
// 1 block = 1 wave = 16 q-rows of one (b,h). Swapped QK^T: lane lr owns
// q-row (q0+lr); its 16 score values per 64-chunk live in-register.
// Online softmax, PV accumulated unnormalized; writes merged + m, 1/l.
struct KF { bf16x8 a[4]; bf16x8 b2[4]; };

__global__ __launch_bounds__(64) void attn_flash(
    const __bf16* __restrict__ Qb, const __bf16* __restrict__ Kb,
    const __bf16* __restrict__ Vt, const float* __restrict__ amask,
    __bf16* __restrict__ merged, float* __restrict__ m_ws,
    float* __restrict__ li_ws) {
  const f32x4 fz = {0.f, 0.f, 0.f, 0.f};
  int id = blockIdx.x;
  int p = id & 127, h = (id >> 7) & 15, b = id >> 11;
  int bh = b * H_ + h;
  int l = threadIdx.x;
  int lr = l & 15, lg = l >> 4;
  const __bf16* Qh = Qb + (size_t)bh * L_ * HD_;
  const __bf16* Kh = Kb + (size_t)bh * L_ * HD_;
  const __bf16* Vh = Vt + (size_t)bh * HD_ * L_;
  const float* mb = amask + (size_t)b * L_;
  int q0 = p * 16;
  int row = q0 + lr;
  int ncc = (p >> 2) + 1;

  __shared__ __bf16 Pl[16 * 72];  // P[q][k], stride 72 bf16

  bf16x8 qf0 = *(const bf16x8*)&Qh[(size_t)row * HD_ + lg * 8];
  bf16x8 qf1 = *(const bf16x8*)&Qh[(size_t)row * HD_ + 32 + lg * 8];

  float m_run = -3.0e38f, l_run = 0.f;
  f32x4 o[4] = {fz, fz, fz, fz};

  auto loadK = [&](int c, KF& kf) {
#pragma unroll
    for (int cf = 0; cf < 4; ++cf) {
      const __bf16* kp = &Kh[(size_t)(c * 64 + cf * 16 + lr) * HD_];
      kf.a[cf]  = *(const bf16x8*)&kp[lg * 8];
      kf.b2[cf] = *(const bf16x8*)&kp[32 + lg * 8];
    }
  };

  auto process = [&](int c, const KF& kf) {
    // issue V loads early; consumed at the end under the softmax VALU
    bf16x8 va[4], vb[4];
#pragma unroll
    for (int dt = 0; dt < 4; ++dt) {
      const __bf16* vp = &Vh[(size_t)(dt * 16 + lr) * L_ + c * 64];
      va[dt] = *(const bf16x8*)&vp[lg * 8];
      vb[dt] = *(const bf16x8*)&vp[32 + lg * 8];
    }
    f32x4 acc[4];
#pragma unroll
    for (int cf = 0; cf < 4; ++cf) {
      acc[cf] = mfma16(kf.a[cf], qf0, fz);
      acc[cf] = mfma16(kf.b2[cf], qf1, acc[cf]);
    }
    float s[4][4];
    float mcf[4];
#pragma unroll
    for (int cf = 0; cf < 4; ++cf) {
#pragma unroll
      for (int jj = 0; jj < 4; ++jj) {
        int col = c * 64 + cf * 16 + lg * 4 + jj;
        float sv = (float)(__bf16)acc[cf][jj] * 0.125f;
        if (col > row) sv = -9984.0f;
        sv += mb[col];
        s[cf][jj] = sv;
      }
      mcf[cf] = fmaxf(fmaxf(s[cf][0], s[cf][1]), fmaxf(s[cf][2], s[cf][3]));
    }
    float mx = fmaxf(fmaxf(mcf[0], mcf[1]), fmaxf(mcf[2], mcf[3]));
    mx = fmaxf(mx, __shfl_xor(mx, 16, 64));
    mx = fmaxf(mx, __shfl_xor(mx, 32, 64));
    float mn = fmaxf(m_run, mx);
    float pp[4][4], scf[4];
#pragma unroll
    for (int cf = 0; cf < 4; ++cf) {
#pragma unroll
      for (int jj = 0; jj < 4; ++jj) pp[cf][jj] = __expf(s[cf][jj] - mn);
      scf[cf] = (pp[cf][0] + pp[cf][1]) + (pp[cf][2] + pp[cf][3]);
    }
    float se = (scf[0] + scf[1]) + (scf[2] + scf[3]);
    se += __shfl_xor(se, 16, 64);
    se += __shfl_xor(se, 32, 64);
    float scale = __expf(m_run - mn);
    l_run = l_run * scale + se;
    m_run = mn;
#pragma unroll
    for (int dt = 0; dt < 4; ++dt) o[dt] *= scale;
    // stage P[q][k] (bf16) for the PV B-operand
#pragma unroll
    for (int cf = 0; cf < 4; ++cf) {
      bf16x4 pk = {(__bf16)pp[cf][0], (__bf16)pp[cf][1], (__bf16)pp[cf][2],
                   (__bf16)pp[cf][3]};
      *(bf16x4*)&Pl[lr * 72 + cf * 16 + lg * 4] = pk;
    }
    bf16x8 pf0 = *(const bf16x8*)&Pl[lr * 72 + lg * 8];
    bf16x8 pf1 = *(const bf16x8*)&Pl[lr * 72 + 32 + lg * 8];
#pragma unroll
    for (int dt = 0; dt < 4; ++dt) {
      o[dt] = mfma16(va[dt], pf0, o[dt]);
      o[dt] = mfma16(vb[dt], pf1, o[dt]);
    }
  };

  KF kA, kB;
  loadK(0, kA);
  int c = 0;
  while (true) {
    if (c + 1 < ncc) loadK(c + 1, kB);
    process(c, kA);
    if (++c >= ncc) break;
    if (c + 1 < ncc) loadK(c + 1, kA);
    process(c, kB);
    if (++c >= ncc) break;
  }

  float linv = 1.0f / l_run;
#pragma unroll
  for (int dt = 0; dt < 4; ++dt) {
    bf16x4 ov = {(__bf16)(o[dt][0] * linv), (__bf16)(o[dt][1] * linv),
                 (__bf16)(o[dt][2] * linv), (__bf16)(o[dt][3] * linv)};
    *(bf16x4*)&merged[((size_t)b * L_ + row) * E_ + h * HD_ + dt * 16 + lg * 4] = ov;
  }
  if (lg == 0) {
    m_ws[(size_t)bh * L_ + row] = m_run;
    li_ws[(size_t)bh * L_ + row] = linv;
  }
}

// ---------------------------------------------------------------- attn write
// 1 block = one 64x64 tile of attn for one (b,h). Upper tiles: vector zeros.
// Lower tiles: recompute S (swapped), p = exp(s-m)*linv, f32x4 stores.
__global__ __launch_bounds__(256) void attn_write(
    const __bf16* __restrict__ Qb, const __bf16* __restrict__ Kb,
    const float* __restrict__ amask, const float* __restrict__ m_ws,
    const float* __restrict__ li_ws, float* __restrict__ attn_out) {
  const f32x4 fz = {0.f, 0.f, 0.f, 0.f};
  int t = blockIdx.x;
  int bh = blockIdx.y;
  int qt = t >> 5, ct = t & 31;
  int b = bh >> 4;
  float* attn = attn_out + (size_t)bh * L_ * L_;

  if (ct > qt) {  // fully-masked tile: exact zeros
    int r = threadIdx.x >> 4, cq = threadIdx.x & 15;
#pragma unroll
    for (int it = 0; it < 4; ++it)
      *(f32x4*)&attn[(size_t)(qt * 64 + it * 16 + r) * L_ + ct * 64 + cq * 4] = fz;
    return;
  }

  int w = threadIdx.x >> 6, l = threadIdx.x & 63;
  int lr = l & 15, lg = l >> 4;
  const __bf16* Qh = Qb + (size_t)bh * L_ * HD_;
  const __bf16* Kh = Kb + (size_t)bh * L_ * HD_;
  const float* mb = amask + (size_t)b * L_;
  int row = qt * 64 + w * 16 + lr;
  bf16x8 qf0 = *(const bf16x8*)&Qh[(size_t)row * HD_ + lg * 8];
  bf16x8 qf1 = *(const bf16x8*)&Qh[(size_t)row * HD_ + 32 + lg * 8];
  float mrow = m_ws[(size_t)bh * L_ + row];
  float lrow = li_ws[(size_t)bh * L_ + row];

#pragma unroll
  for (int cf = 0; cf < 4; ++cf) {
    const __bf16* kp = &Kh[(size_t)(ct * 64 + cf * 16 + lr) * HD_];
    bf16x8 ka  = *(const bf16x8*)&kp[lg * 8];
    bf16x8 kb2 = *(const bf16x8*)&kp[32 + lg * 8];
    f32x4 acc = mfma16(ka, qf0, fz);
    acc = mfma16(kb2, qf1, acc);
    f32x4 pv;
#pragma unroll
    for (int jj = 0; jj < 4; ++jj) {
      int col = ct * 64 + cf * 16 + lg * 4 + jj;
      float sv = (float)(__bf16)acc[jj] * 0.125f;
      if (col > row) sv = -9984.0f;
      sv += mb[col];
      pv[jj] = __expf(sv - mrow) * lrow;
    }
    *(f32x4*)&attn[(size_t)row * L_ + ct * 64 + cf * 16 + lg * 4] = pv;
  }
}

// ---------------------------------------------------------------- launch
extern "C" void kernel_launch(void* const* d_in, const int* in_sizes, int n_in,
                              void* d_out, int out_size, void* d_ws,
                              size_t ws_size, hipStream_t stream) {
  const float* x     = (const float*)d_in[0];
  const float* amask = (const float*)d_in[1];
  const float* W_in  = (const float*)d_in[2];
  const float* b_in  = (const float*)d_in[3];
  const float* W_out = (const float*)d_in[4];
  const float* b_out = (const float*)d_in[5];

  float* out  = (float*)d_out;
  float* attn = out + (size_t)B_ * L_ * E_;

  char* ws = (char*)d_ws;
  __bf16* xb     = (__bf16*)(ws + 0);
  __bf16* WtIn   = (__bf16*)(ws + 8388608);
  __bf16* WtOut  = (__bf16*)(ws + 14680064);
  __bf16* Qb     = (__bf16*)(ws + 16777216);
  __bf16* Kb     = (__bf16*)(ws + 25165824);
  __bf16* Vt     = (__bf16*)(ws + 33554432);
  __bf16* merged = (__bf16*)(ws + 41943040);

  // m, 1/l live in the `out` region of d_out: written by attn_flash, read by
  // attn_write, then dead before the final GEMM overwrites `out`.
  float* m_ws  = out;
  float* li_ws = out + B_ * H_ * L_;

  int nx = B_ * L_ * E_;
  f32_to_bf16_vec<<<nx / (256 * 4), 256, 0, stream>>>(x, xb, nx);
  transpose_to_bf16<<<dim3(3 * E_ / 32, E_ / 32), dim3(32, 8), 0, stream>>>(
      W_in, WtIn, E_, 3 * E_);
  transpose_to_bf16<<<dim3(E_ / 32, E_ / 32), dim3(32, 8), 0, stream>>>(
      W_out, WtOut, E_, E_);

  gemm_bf16_k<<<dim3(3 * E_ / 128, B_ * L_ / 128), 256, 0, stream>>>(
      xb, WtIn, b_in, B_ * L_, 3 * E_, E_, 0, nullptr, Qb, Kb, Vt);

  attn_flash<<<B_ * H_ * (L_ / 16), 64, 0, stream>>>(Qb, Kb, Vt, amask,
                                                     merged, m_ws, li_ws);

  attn_write<<<dim3(32 * 32, B_ * H_), 256, 0, stream>>>(Qb, Kb, amask, m_ws,
                                                         li_ws, attn);

  gemm_bf16_k<<<dim3(E_ / 128, B_ * L_ / 128), 256, 0, stream>>>(
      merged, WtOut, b_out, B_ * L_, E_, E_, 1, out, nullptr, nullptr,
      nullptr);
}

// Round 3
// 313.448 us; speedup vs baseline: 1.5844x; 1.5801x over previous
//
#include <hip/hip_runtime.h>

// GPT2 self-attention fused pipeline for MI355X (gfx950).
// B=2, L=2048, E=1024, H=16, HD=64.
// d_out = [out (B*L*E f32)] ++ [attn (B*H*L*L f32)]

#define B_ 2
#define L_ 2048
#define E_ 1024
#define H_ 16
#define HD_ 64

typedef __attribute__((ext_vector_type(8))) __bf16 bf16x8;
typedef __attribute__((ext_vector_type(4))) __bf16 bf16x4;
typedef __attribute__((ext_vector_type(4))) float f32x4;

typedef __attribute__((address_space(1))) const void gvoid_t;
typedef __attribute__((address_space(3))) void lvoid_t;

__device__ __forceinline__ void g2l16(const void* g, void* l) {
  // async global->LDS: LDS dest = wave-uniform base + lane*16; global src per-lane
  __builtin_amdgcn_global_load_lds((gvoid_t*)g, (lvoid_t*)l, 16, 0, 0);
}

__device__ __forceinline__ f32x4 mfma16(bf16x8 a, bf16x8 b, f32x4 c) {
  return __builtin_amdgcn_mfma_f32_16x16x32_bf16(a, b, c, 0, 0, 0);
}

// ---------------------------------------------------------------- converts
__global__ __launch_bounds__(256) void f32_to_bf16_vec(
    const float* __restrict__ in, __bf16* __restrict__ out, int n) {
  int i = (blockIdx.x * blockDim.x + threadIdx.x) * 4;
  if (i >= n) return;
  float4 v = *(const float4*)(in + i);
  bf16x4 o = {(__bf16)v.x, (__bf16)v.y, (__bf16)v.z, (__bf16)v.w};
  *(bf16x4*)(out + i) = o;
}

// out[c][r] = (bf16) in[r][c]   (in: [R][C] f32 row-major)
__global__ __launch_bounds__(256) void transpose_to_bf16(
    const float* __restrict__ in, __bf16* __restrict__ out, int R, int C) {
  __shared__ __bf16 tile[32][33];
  int c0 = blockIdx.x * 32, r0 = blockIdx.y * 32;
  int tx = threadIdx.x, ty = threadIdx.y;
  for (int i = ty; i < 32; i += 8)
    tile[i][tx] = (__bf16)in[(size_t)(r0 + i) * C + c0 + tx];
  __syncthreads();
  for (int i = ty; i < 32; i += 8)
    out[(size_t)(c0 + i) * R + r0 + tx] = tile[tx][i];
}

// ---------------------------------------------------------------- GEMM
// C[M][N] = A[M][K] @ Bt[N][K]^T  (+bias[n]).  bf16 inputs, fp32 accum.
// mode 0: QKV epilogue scatter -> Qb/Kb [bh][L][64] bf16, Vt [bh][64][L] bf16
// mode 1: outF[m][n] = acc + bias  (f32)
__global__ __launch_bounds__(256) void gemm_bf16_k(
    const __bf16* __restrict__ A, const __bf16* __restrict__ Bt,
    const float* __restrict__ bias, int M, int N, int K, int mode,
    float* __restrict__ outF, __bf16* __restrict__ Qb,
    __bf16* __restrict__ Kb, __bf16* __restrict__ Vt) {
  const f32x4 fz = {0.f, 0.f, 0.f, 0.f};
  int n0 = blockIdx.x * 128, m0 = blockIdx.y * 128;
  int w = threadIdx.x >> 6, l = threadIdx.x & 63;
  int wr = w >> 1, wc = w & 1, lr = l & 15, lg = l >> 4;
  __shared__ __bf16 Al[128 * 64];
  __shared__ __bf16 Bl[128 * 64];
  f32x4 acc[4][4];
#pragma unroll
  for (int i = 0; i < 4; ++i)
#pragma unroll
    for (int j = 0; j < 4; ++j) acc[i][j] = fz;

  for (int k0 = 0; k0 < K; k0 += 64) {
    __syncthreads();
#pragma unroll
    for (int i = 0; i < 4; ++i) {
      int base = (w * 4 + i) * 1024;
      int boff = base + l * 16;
      int row = boff >> 7, ch = (boff >> 4) & 7;
      g2l16(A + (size_t)(m0 + row) * K + k0 + ch * 8, (char*)Al + base);
      g2l16(Bt + (size_t)(n0 + row) * K + k0 + ch * 8, (char*)Bl + base);
    }
    __syncthreads();
    bf16x8 af[2][4], bfr[2][4];
#pragma unroll
    for (int ks = 0; ks < 2; ++ks)
#pragma unroll
      for (int f = 0; f < 4; ++f) {
        af[ks][f]  = *(const bf16x8*)&Al[(wr * 64 + f * 16 + lr) * 64 + ks * 32 + lg * 8];
        bfr[ks][f] = *(const bf16x8*)&Bl[(wc * 64 + f * 16 + lr) * 64 + ks * 32 + lg * 8];
      }
#pragma unroll
    for (int ks = 0; ks < 2; ++ks)
#pragma unroll
      for (int mf = 0; mf < 4; ++mf)
#pragma unroll
        for (int nf = 0; nf < 4; ++nf)
          acc[mf][nf] = mfma16(af[ks][mf], bfr[ks][nf], acc[mf][nf]);
  }

#pragma unroll
  for (int mf = 0; mf < 4; ++mf)
#pragma unroll
    for (int nf = 0; nf < 4; ++nf) {
      int ncol = n0 + wc * 64 + nf * 16 + lr;
      float bv = bias[ncol];
#pragma unroll
      for (int jj = 0; jj < 4; ++jj) {
        int mr = m0 + wr * 64 + mf * 16 + lg * 4 + jj;
        float v = acc[mf][nf][jj] + bv;
        if (mode == 1) {
          outF[(size_t)mr * N + ncol] = v;
        } else {
          int bb = mr >> 11, lp = mr & 2047;
          int reg = ncol >> 10, nn = ncol & 1023;
          int hh = nn >> 6, dd = nn & 63;
          size_t bh = (size_t)bb * H_ + hh;
          __bf16 bv16 = (__bf16)v;
          if (reg == 0)      Qb[(bh * L_ + lp) * HD_ + dd] = bv16;
          else if (reg == 1) Kb[(bh * L_ + lp) * HD_ + dd] = bv16;
          else               Vt[(bh * HD_ + dd) * L_ + lp] = bv16;
        }
      }
    }
}

// ---------------------------------------------------------------- attention
// 1 block = 4 waves = 64 q-rows of one (b,h). Swapped QK^T (lane owns q-row).
// K staged coalesced into LDS (XOR-swizzled, double-buffered), shared by all
// 4 waves. Pass1: online m,l (K only). Pass2: recompute S, write fp32 attn,
// PV from LDS-staged V. Upper-triangle chunks: trailing barrier-free zeros.
// Block order: qt descending (big work first); bh%8 == blockIdx%8 -> each XCD
// serves a fixed 4-head K/V working set (~2MB, L2-resident).
__global__ __launch_bounds__(256) void attn_fused2(
    const __bf16* __restrict__ Qb, const __bf16* __restrict__ Kb,
    const __bf16* __restrict__ Vt, const float* __restrict__ amask,
    float* __restrict__ attn_out, __bf16* __restrict__ merged) {
  const f32x4 fz = {0.f, 0.f, 0.f, 0.f};
  int id = blockIdx.x;
  int bh = id & 31;
  int qt = 31 - (id >> 5);
  int b = bh >> 4, h = bh & 15;
  int w = threadIdx.x >> 6, l = threadIdx.x & 63;
  int lr = l & 15, lg = l >> 4;
  const __bf16* Qh = Qb + (size_t)bh * L_ * HD_;
  const char* Kc = (const char*)(Kb + (size_t)bh * L_ * HD_);
  const char* Vc = (const char*)(Vt + (size_t)bh * HD_ * L_);
  float* attn = attn_out + (size_t)bh * L_ * L_;
  const float* mb = amask + (size_t)b * L_;
  int rowq = qt * 64 + w * 16 + lr;

  __shared__ __bf16 Kl[2][64 * 64];  // [row][64] 128B rows, XOR-swizzled
  __shared__ __bf16 Vl[64 * 64];
  __shared__ __bf16 Pl[4][16 * 72];  // per-wave P, padded stride

  bf16x8 qf0 = *(const bf16x8*)&Qh[(size_t)rowq * HD_ + lg * 8];
  bf16x8 qf1 = *(const bf16x8*)&Qh[(size_t)rowq * HD_ + 32 + lg * 8];

  // stage: lds[row][c8] = G[row][c8 ^ (row&7)]  (16B units) -- linear dest,
  // pre-swizzled per-lane global source (rule #21).
  auto stageK = [&](int c, int buf) {
#pragma unroll
    for (int i = 0; i < 2; ++i) {
      int seg = w * 2 + i;
      int grow = seg * 8 + (l >> 3);
      int sc8 = (l & 7) ^ (grow & 7);
      g2l16(Kc + (size_t)c * 8192 + grow * 128 + sc8 * 16,
            (char*)&Kl[buf][0] + seg * 1024);
    }
  };
  auto stageV = [&](int c) {
#pragma unroll
    for (int i = 0; i < 2; ++i) {
      int seg = w * 2 + i;
      int grow = seg * 8 + (l >> 3);
      int sc8 = (l & 7) ^ (grow & 7);
      g2l16(Vc + (size_t)grow * 4096 + (size_t)c * 128 + sc8 * 16,
            (char*)&Vl[0] + seg * 1024);
    }
  };
  // swizzled fragment read: T[row][ (hf*4+lg)*8 .. +8 ]
  auto readT = [&](const __bf16* base, int row, int hf) -> bf16x8 {
    int c8 = (hf * 4 + lg) ^ (lr & 7);
    return *(const bf16x8*)((const char*)base + row * 128 + c8 * 16);
  };

  float m_run = -3.0e38f, l_run = 0.f;
  int ncc = qt + 1;

  // ---------------- pass 1: online m, l
  stageK(0, 0);
  __syncthreads();
  int cur = 0;
  for (int c = 0; c < ncc; ++c) {
    if (c + 1 < ncc) stageK(c + 1, cur ^ 1);
    f32x4 acc[4];
#pragma unroll
    for (int cf = 0; cf < 4; ++cf) {
      acc[cf] = mfma16(readT(Kl[cur], cf * 16 + lr, 0), qf0, fz);
      acc[cf] = mfma16(readT(Kl[cur], cf * 16 + lr, 1), qf1, acc[cf]);
    }
    float s[4][4], mcf[4];
#pragma unroll
    for (int cf = 0; cf < 4; ++cf) {
#pragma unroll
      for (int jj = 0; jj < 4; ++jj) {
        int col = c * 64 + cf * 16 + lg * 4 + jj;
        float sv = (float)(__bf16)acc[cf][jj] * 0.125f;
        if (col > rowq) sv = -9984.0f;
        s[cf][jj] = sv + mb[col];
      }
      mcf[cf] = fmaxf(fmaxf(s[cf][0], s[cf][1]), fmaxf(s[cf][2], s[cf][3]));
    }
    float mx = fmaxf(fmaxf(mcf[0], mcf[1]), fmaxf(mcf[2], mcf[3]));
    mx = fmaxf(mx, __shfl_xor(mx, 16, 64));
    mx = fmaxf(mx, __shfl_xor(mx, 32, 64));
    float mn = fmaxf(m_run, mx);
    float se = 0.f;
#pragma unroll
    for (int cf = 0; cf < 4; ++cf) {
      float e0 = __expf(s[cf][0] - mn), e1 = __expf(s[cf][1] - mn);
      float e2 = __expf(s[cf][2] - mn), e3 = __expf(s[cf][3] - mn);
      se += (e0 + e1) + (e2 + e3);
    }
    se += __shfl_xor(se, 16, 64);
    se += __shfl_xor(se, 32, 64);
    l_run = l_run * __expf(m_run - mn) + se;
    m_run = mn;
    __syncthreads();  // K[c+1] resident; readers of Kl[cur] done
    cur ^= 1;
  }
  float linv = 1.0f / l_run;

  // ---------------- pass 2: recompute S, write attn, PV
  f32x4 o[4] = {fz, fz, fz, fz};
  stageK(0, 0);
  __syncthreads();
  cur = 0;
  for (int c = 0; c < ncc; ++c) {
    stageV(c);  // safe: prev iter's tail barrier passed (PV reads done)
    if (c + 1 < ncc) stageK(c + 1, cur ^ 1);
    f32x4 acc[4];
#pragma unroll
    for (int cf = 0; cf < 4; ++cf) {
      acc[cf] = mfma16(readT(Kl[cur], cf * 16 + lr, 0), qf0, fz);
      acc[cf] = mfma16(readT(Kl[cur], cf * 16 + lr, 1), qf1, acc[cf]);
    }
#pragma unroll
    for (int cf = 0; cf < 4; ++cf) {
      f32x4 pv;
#pragma unroll
      for (int jj = 0; jj < 4; ++jj) {
        int col = c * 64 + cf * 16 + lg * 4 + jj;
        float sv = (float)(__bf16)acc[cf][jj] * 0.125f;
        if (col > rowq) sv = -9984.0f;
        pv[jj] = __expf(sv + mb[col] - m_run) * linv;
      }
      *(f32x4*)&attn[(size_t)rowq * L_ + c * 64 + cf * 16 + lg * 4] = pv;
      bf16x4 pk = {(__bf16)pv[0], (__bf16)pv[1], (__bf16)pv[2], (__bf16)pv[3]};
      *(bf16x4*)&Pl[w][lr * 72 + cf * 16 + lg * 4] = pk;
    }
    __syncthreads();  // V[c] (+K[c+1]) resident
    bf16x8 pf0 = *(const bf16x8*)&Pl[w][lr * 72 + lg * 8];
    bf16x8 pf1 = *(const bf16x8*)&Pl[w][lr * 72 + 32 + lg * 8];
#pragma unroll
    for (int dt = 0; dt < 4; ++dt) {
      o[dt] = mfma16(readT(Vl, dt * 16 + lr, 0), pf0, o[dt]);
      o[dt] = mfma16(readT(Vl, dt * 16 + lr, 1), pf1, o[dt]);
    }
    __syncthreads();  // PV reads done before next-iter V/K overwrite
    cur ^= 1;
  }

  // merged head outputs (already normalized)
#pragma unroll
  for (int dt = 0; dt < 4; ++dt) {
    bf16x4 ov = {(__bf16)o[dt][0], (__bf16)o[dt][1], (__bf16)o[dt][2],
                 (__bf16)o[dt][3]};
    *(bf16x4*)&merged[((size_t)b * L_ + rowq) * E_ + h * HD_ + dt * 16 + lg * 4] = ov;
  }

  // barrier-free zero tail: fully-masked chunks (exact 0 in ref softmax)
  for (int c = ncc; c < 32; ++c)
#pragma unroll
    for (int q = 0; q < 4; ++q)
      *(f32x4*)&attn[(size_t)rowq * L_ + c * 64 + q * 16 + lg * 4] = fz;
}

// ---------------------------------------------------------------- launch
extern "C" void kernel_launch(void* const* d_in, const int* in_sizes, int n_in,
                              void* d_out, int out_size, void* d_ws,
                              size_t ws_size, hipStream_t stream) {
  const float* x     = (const float*)d_in[0];
  const float* amask = (const float*)d_in[1];
  const float* W_in  = (const float*)d_in[2];
  const float* b_in  = (const float*)d_in[3];
  const float* W_out = (const float*)d_in[4];
  const float* b_out = (const float*)d_in[5];

  float* out  = (float*)d_out;
  float* attn = out + (size_t)B_ * L_ * E_;

  char* ws = (char*)d_ws;
  __bf16* xb     = (__bf16*)(ws + 0);
  __bf16* WtIn   = (__bf16*)(ws + 8388608);
  __bf16* WtOut  = (__bf16*)(ws + 14680064);
  __bf16* Qb     = (__bf16*)(ws + 16777216);
  __bf16* Kb     = (__bf16*)(ws + 25165824);
  __bf16* Vt     = (__bf16*)(ws + 33554432);
  __bf16* merged = (__bf16*)(ws + 41943040);

  int nx = B_ * L_ * E_;
  f32_to_bf16_vec<<<nx / (256 * 4), 256, 0, stream>>>(x, xb, nx);
  transpose_to_bf16<<<dim3(3 * E_ / 32, E_ / 32), dim3(32, 8), 0, stream>>>(
      W_in, WtIn, E_, 3 * E_);
  transpose_to_bf16<<<dim3(E_ / 32, E_ / 32), dim3(32, 8), 0, stream>>>(
      W_out, WtOut, E_, E_);

  gemm_bf16_k<<<dim3(3 * E_ / 128, B_ * L_ / 128), 256, 0, stream>>>(
      xb, WtIn, b_in, B_ * L_, 3 * E_, E_, 0, nullptr, Qb, Kb, Vt);

  attn_fused2<<<32 * 32, 256, 0, stream>>>(Qb, Kb, Vt, amask, attn, merged);

  gemm_bf16_k<<<dim3(E_ / 128, B_ * L_ / 128), 256, 0, stream>>>(
      merged, WtOut, b_out, B_ * L_, E_, E_, 1, out, nullptr, nullptr,
      nullptr);
}